// Round 16
// baseline (288.899 us; speedup 1.0000x reference)
//
#include <hip/hip_runtime.h>
#include <hip/hip_bf16.h>

// RelationalNet forward, MI355X (gfx950).  6 graph nodes:
// prep_w_zero: gw2/3/4 -> bf16 fragment order, zero BN stat accumulators
// conv1..4: PX horizontal output px per thread (stride-2 windows share cols:
//           one ci-round = (2PX+1)x3 input burst + 72 s_load weights (COG=8,
//           fits SGPR budget) -> PX*72 FMAs, 4:1 weight reuse). Dynamic ci
//           loop stops weight hoisting. BN stats via 8-shadow atomicAdd; BN of
//           layer l finalized in the CONSUMER's preamble.
// g_mega (1 block/batch, 512 thr): BN4 reduce + obj + A'/Bm LDS -> 5 x
//           {act-init; 3 layers 256x256 bf16 MFMA; row-sum} -> inline f_phi.
// Workspace: 13,296,832 floats = 53.2 MB.

typedef __attribute__((ext_vector_type(8))) short short8;
typedef __attribute__((ext_vector_type(4))) float floatx4;

__device__ __forceinline__ unsigned short f2bf(float v){
  union { float f; unsigned int u; } c; c.f = v;
  unsigned int u = c.u;
  u += 0x7FFFu + ((u >> 16) & 1u);   // round-to-nearest-even
  return (unsigned short)(u >> 16);
}

// ------------- gw2/3/4 f32 -> bf16 in MFMA B-fragment order; zero stats -------------
// wf[w][((kk*16 + t)*64 + lane)*8 + i] = W[kk*32 + (lane>>4)*8 + i][t*16 + (lane&15)]
__global__ __launch_bounds__(256) void prep_w_zero(
    const float* __restrict__ gw2, const float* __restrict__ gw3,
    const float* __restrict__ gw4, unsigned short* __restrict__ wf,
    float* __restrict__ stats)
{
  const int bid = blockIdx.x, tid = threadIdx.x;      // grid 768
  if (bid == 0){ for (int j = tid; j < 1536; j += 256) stats[j] = 0.f; }
  const int w = bid >> 8;
  const float* gw = (w == 0) ? gw2 : (w == 1) ? gw3 : gw4;
  const int idx = (bid & 255)*256 + tid;              // 65536 per weight
  const int i = idx & 7, lane = (idx >> 3) & 63, t = (idx >> 9) & 15, kk = idx >> 13;
  const int k = kk*32 + (lane >> 4)*8 + i;
  const int c = t*16 + (lane & 15);
  wf[w*65536 + idx] = f2bf(gw[k*256 + c]);
}

// ------------- conv + relu + BN stats; PX px/thread, COG=8, per-ci weight rounds -------------
template<int CI, int COG, int PX>
__global__ __launch_bounds__(256) void conv_px(
    const float* __restrict__ in,
    const float* __restrict__ stats_in, const float* __restrict__ gprev,
    const float* __restrict__ bprev, float invN,
    const float* __restrict__ cw, const float* __restrict__ cb,
    float* __restrict__ out, float* __restrict__ stats_out,
    int H, int W, int OH, int OW)
{
  const int co0 = blockIdx.y * COG;
  __shared__ float ssm[2*CI];
  __shared__ float psum[4][COG], psum2[4][COG];
  const int tid = threadIdx.x;
  if (tid < CI){
    if (stats_in){
      float S = 0.f, S2 = 0.f;
      #pragma unroll
      for (int sh = 0; sh < 8; sh++){ S += stats_in[sh*48 + tid]; S2 += stats_in[sh*48 + 24 + tid]; }
      const float mean = S*invN;
      const float var  = S2*invN - mean*mean;    // biased var (ddof=0) = jnp.var
      const float rs   = rsqrtf(var + 1e-5f);
      const float sc   = gprev[tid]*rs;
      ssm[tid] = sc; ssm[CI + tid] = bprev[tid] - mean*sc;
    } else { ssm[tid] = 1.f; ssm[CI + tid] = 0.f; }
  }
  __syncthreads();
  const int nw = OW / PX;                        // exact (PX chosen per layer)
  const int idx = blockIdx.x*256 + tid;          // grids exact multiples of 256
  const int pw = idx % nw; const int t2 = idx / nw;
  const int oh = t2 % OH;  const int b  = t2 / OH;
  const int ow0 = pw * PX;
  const float* cwb = cw + co0*CI*9;              // wave-uniform -> s_load
  constexpr int NC = 2*PX + 1;
  float acc[PX][COG];
  #pragma unroll
  for (int j = 0; j < PX; j++)
    #pragma unroll
    for (int g = 0; g < COG; g++) acc[j][g] = cb[co0 + g];

  #pragma unroll 1                               // dynamic ci: 72 live weights, not CI*72
  for (int ci = 0; ci < CI; ci++){
    const float* ip = in + ((long)(b*CI + ci))*H*W;
    const float sc = ssm[ci], sh2 = ssm[CI + ci];
    float v[3][NC];
    #pragma unroll
    for (int kh = 0; kh < 3; kh++){
      const int ih = oh*2 - 1 + kh;              // max 2*OH-1 = H-1, only <0 possible
      const bool hok = (ih >= 0);
      #pragma unroll
      for (int c9 = 0; c9 < NC; c9++){
        const int iw = ow0*2 - 1 + c9;           // max 2*OW-1 = W-1, only <0 possible
        const bool ok = hok & (iw >= 0);
        const float raw = ip[ok ? ih*W + iw : 0];    // unconditional load, clamped addr
        v[kh][c9] = ok ? raw*sc + sh2 : 0.f;         // zero-pad after BN fold
      }
    }
    #pragma unroll
    for (int g = 0; g < COG; g++){
      #pragma unroll
      for (int kh = 0; kh < 3; kh++){
        const float w0 = cwb[(g*CI + ci)*9 + kh*3 + 0];
        const float w1 = cwb[(g*CI + ci)*9 + kh*3 + 1];
        const float w2 = cwb[(g*CI + ci)*9 + kh*3 + 2];
        #pragma unroll
        for (int j = 0; j < PX; j++)
          acc[j][g] += v[kh][2*j]*w0 + v[kh][2*j+1]*w1 + v[kh][2*j+2]*w2;
      }
    }
  }

  const int wave = tid >> 6, lane = tid & 63;
  float s[COG], s2[COG];
  #pragma unroll
  for (int g = 0; g < COG; g++){
    float tmp[PX], a = 0.f, a2 = 0.f;
    #pragma unroll
    for (int j = 0; j < PX; j++){
      tmp[j] = fmaxf(acc[j][g], 0.f);
      a += tmp[j]; a2 += tmp[j]*tmp[j];
    }
    float* op = &out[(((long)b*24 + co0 + g)*OH + oh)*OW + ow0];
    if constexpr (PX == 4) *(float4*)op = make_float4(tmp[0], tmp[1], tmp[2], tmp[3]);
    else if constexpr (PX == 2) *(float2*)op = make_float2(tmp[0], tmp[1]);
    else op[0] = tmp[0];
    s[g] = a; s2[g] = a2;
  }
  #pragma unroll
  for (int g = 0; g < COG; g++){
    float a = s[g], a2 = s2[g];
    for (int off = 32; off; off >>= 1){ a += __shfl_down(a, off); a2 += __shfl_down(a2, off); }
    if (lane == 0){ psum[wave][g] = a; psum2[wave][g] = a2; }
  }
  __syncthreads();
  if (tid < COG){
    const float S  = psum[0][tid] + psum[1][tid] + psum[2][tid] + psum[3][tid];
    const float S2 = psum2[0][tid] + psum2[1][tid] + psum2[2][tid] + psum2[3][tid];
    const int sh = blockIdx.x & 7;               // 8 shadows cut same-address serialization
    atomicAdd(&stats_out[sh*48 + co0 + tid],      S);
    atomicAdd(&stats_out[sh*48 + 24 + co0 + tid], S2);
  }
}

// ------ g_mega: BN4 + obj + A'/Bm (LDS) + 5x(act-init; 3-layer MFMA; rowsum) + f_phi ------
__global__ __launch_bounds__(512) void g_mega(
    const float* __restrict__ y4, const float* __restrict__ stats4,
    const float* __restrict__ bg4, const float* __restrict__ bb4,
    const float* __restrict__ qst, const float* __restrict__ gw1,
    const float* __restrict__ gb1,
    const unsigned short* __restrict__ Wf,
    const float* __restrict__ gb2, const float* __restrict__ gb3, const float* __restrict__ gb4,
    const float* __restrict__ fw1, const float* __restrict__ fb1,
    const float* __restrict__ fw2, const float* __restrict__ fb2,
    const float* __restrict__ fw3, const float* __restrict__ fb3,
    float* __restrict__ out)
{
  __shared__ __align__(16) short act[128*256];      // 64 KB
  __shared__ __align__(16) float A_lds[25][260];    // 26 KB (A + Qv folded)
  __shared__ __align__(16) float Bm_lds[25][260];   // 26 KB
  __shared__ float obj[25][26];
  __shared__ float ssum[48];
  __shared__ float ssm[48];
  __shared__ float scratch[512];
  __shared__ __align__(16) float bufA[256], bufB[256];
  __shared__ float lg[10];

  const int b = blockIdx.x, tid = threadIdx.x;
  char* actB = (char*)act;
  const int wave = tid >> 6, lane = tid & 63;
  const int lmod = lane & 15, ldiv = lane >> 4;
  const int wm = wave >> 2, wn = wave & 3;          // 2 x 4 wave grid

  // ---- BN4 reduce (8 shadows) + finalize ----
  if (tid < 48){
    float S = 0.f;
    #pragma unroll
    for (int sh = 0; sh < 8; sh++) S += stats4[sh*48 + tid];
    ssum[tid] = S;
  }
  __syncthreads();
  if (tid < 24){
    const float mean = ssum[tid]*(1.f/6400.f);
    const float var  = ssum[24 + tid]*(1.f/6400.f) - mean*mean;
    const float rs   = rsqrtf(var + 1e-5f);
    const float sc   = bg4[tid]*rs;
    ssm[tid] = sc; ssm[24 + tid] = bb4[tid] - mean*sc;
  }
  __syncthreads();
  // ---- obj (BN-folded y4 + coords) ----
  for (int j = tid; j < 600; j += 512){
    const int q = j/24, c = j%24;
    obj[q][c] = ssm[c]*y4[((long)(b*24 + c))*25 + q] + ssm[24 + c];
  }
  if (tid < 50){
    const int q = tid >> 1;
    obj[q][24 + (tid & 1)] = (tid & 1) ? (float)(q%5 - 2)*0.5f : (float)(q/5 - 2)*0.5f;
  }
  __syncthreads();
  // ---- A'(=A+Qv), Bm into LDS; halves split the q range ----
  {
    const int n = tid & 255, half = tid >> 8;
    float wa[26], wb[26];
    #pragma unroll
    for (int c = 0; c < 26; c++){ wa[c] = gw1[c*256 + n]; wb[c] = gw1[(26 + c)*256 + n]; }
    float qv = gb1[n];
    #pragma unroll
    for (int j = 0; j < 11; j++) qv += qst[b*11 + j]*gw1[(52 + j)*256 + n];
    const int q0 = half ? 13 : 0, q1 = half ? 25 : 13;
    for (int q = q0; q < q1; q++){
      float a = qv, bm = 0.f;
      #pragma unroll
      for (int c = 0; c < 26; c++){ const float o = obj[q][c]; a += o*wa[c]; bm += o*wb[c]; }
      A_lds[q][n] = a; Bm_lds[q][n] = bm;
    }
  }
  __syncthreads();

  float gsum = 0.f;
  for (int blk = 0; blk < 5; blk++){
    const int rowbase = blk * 128;
    const int nrows = min(128, 625 - rowbase);      // last chunk: 113
    // ---- act-init: act = relu(A'[q] + Bm[p]), bf16, swizzled ----
    {
      const int r  = tid >> 2;
      const int q4 = tid & 3;
      if (r < nrows){
        const int row = rowbase + r;                // pair index p*25+q
        const float* ap = &A_lds [row % 25][q4*4];
        const float* bp = &Bm_lds[row / 25][q4*4];
        #pragma unroll
        for (int j = 0; j < 16; j++){
          const int c = j*16;
          floatx4 av = *(const floatx4*)(ap + c);
          floatx4 bv = *(const floatx4*)(bp + c);
          unsigned int p0 = (unsigned int)f2bf(fmaxf(av.x+bv.x, 0.f))
                          | ((unsigned int)f2bf(fmaxf(av.y+bv.y, 0.f)) << 16);
          unsigned int p1 = (unsigned int)f2bf(fmaxf(av.z+bv.z, 0.f))
                          | ((unsigned int)f2bf(fmaxf(av.w+bv.w, 0.f)) << 16);
          const int byte = (r*512 + (c + q4*4)*2) ^ ((r & 7) << 4);
          *(uint2*)(actB + byte) = make_uint2(p0, p1);
        }
      } else {
        #pragma unroll
        for (int j = 0; j < 16; j++){
          const int byte = (r*512 + (j*16 + q4*4)*2) ^ ((r & 7) << 4);
          *(uint2*)(actB + byte) = make_uint2(0u, 0u); // padded rows zero (masked)
        }
      }
    }
    __syncthreads();

    for (int L = 0; L < 3; L++){
      floatx4 acc[4][4];
      #pragma unroll
      for (int m = 0; m < 4; m++)
        #pragma unroll
        for (int n = 0; n < 4; n++)
          acc[m][n] = (floatx4){0.f,0.f,0.f,0.f};
      const short8* wlayer = (const short8*)Wf + (long)L*8192;
      #pragma unroll
      for (int kk = 0; kk < 8; kk++){
        short8 bf[4];
        #pragma unroll
        for (int n = 0; n < 4; n++)
          bf[n] = wlayer[(kk*16 + wn*4 + n)*64 + lane];   // coalesced, L2-hot
        short8 af[4];
        #pragma unroll
        for (int m = 0; m < 4; m++){
          const int arow  = wm*64 + m*16 + lmod;
          const int abyte = (arow*512 + kk*64 + ldiv*16) ^ ((arow & 7) << 4);
          af[m] = *(const short8*)(actB + abyte);
        }
        #pragma unroll
        for (int n = 0; n < 4; n++)
          #pragma unroll
          for (int m = 0; m < 4; m++)
            acc[m][n] = __builtin_amdgcn_mfma_f32_16x16x32_bf16(af[m], bf[n], acc[m][n], 0, 0, 0);
      }

      if (L < 2){
        const float* bias = (L == 0) ? gb2 : gb3;
        __syncthreads();   // WAR: all act reads done before overwrite
        // D layout: row = m*16 + ldiv*4 + i, col = (wn*4+n)*16 + lmod   [m89]
        #pragma unroll
        for (int n = 0; n < 4; n++){
          const int c = (wn*4 + n)*16 + lmod;
          const float bv = bias[c];
          #pragma unroll
          for (int m = 0; m < 4; m++){
            #pragma unroll
            for (int i = 0; i < 4; i++){
              const int row = wm*64 + m*16 + ldiv*4 + i;
              const float v = fmaxf(acc[m][n][i] + bv, 0.f);
              const int byte = (row*512 + c*2) ^ ((row & 7) << 4);
              *(short*)(actB + byte) = (short)f2bf(v);
            }
          }
        }
        __syncthreads();   // new act visible
      } else {
        __syncthreads();   // all act reads + prior scratch reads done
        #pragma unroll
        for (int n = 0; n < 4; n++){
          const int c = (wn*4 + n)*16 + lmod;
          const float bv = gb4[c];
          float sv = 0.f;
          #pragma unroll
          for (int m = 0; m < 4; m++){
            #pragma unroll
            for (int i = 0; i < 4; i++){
              const int row = wm*64 + m*16 + ldiv*4 + i;
              const float v = fmaxf(acc[m][n][i] + bv, 0.f);
              if (row < nrows) sv += v;             // mask padded rows
            }
          }
          sv += __shfl_xor(sv, 16);
          sv += __shfl_xor(sv, 32);
          if (ldiv == 0) scratch[wm*256 + c] = sv;
        }
        __syncthreads();
        if (tid < 256) gsum += scratch[tid] + scratch[256 + tid];
      }
    }
  }

  // ---- inline f_phi + log_softmax ----
  if (tid < 256) bufA[tid] = gsum;
  __syncthreads();
  const int n = tid & 255;
  float acc = 0.f;
  if (tid < 256){
    acc = fb1[n];
    const float4* pa = (const float4*)bufA;
    #pragma unroll 8
    for (int k4 = 0; k4 < 64; k4++){
      const float4 a = pa[k4];
      acc += a.x*fw1[(k4*4 + 0)*256 + n];
      acc += a.y*fw1[(k4*4 + 1)*256 + n];
      acc += a.z*fw1[(k4*4 + 2)*256 + n];
      acc += a.w*fw1[(k4*4 + 3)*256 + n];
    }
    bufB[n] = fmaxf(acc, 0.f);
  }
  __syncthreads();
  if (tid < 256){
    acc = fb2[n];
    const float4* pb = (const float4*)bufB;
    #pragma unroll 8
    for (int k4 = 0; k4 < 64; k4++){
      const float4 a = pb[k4];
      acc += a.x*fw2[(k4*4 + 0)*256 + n];
      acc += a.y*fw2[(k4*4 + 1)*256 + n];
      acc += a.z*fw2[(k4*4 + 2)*256 + n];
      acc += a.w*fw2[(k4*4 + 3)*256 + n];
    }
  }
  __syncthreads();          // bufB reads done
  if (tid < 256) bufA[n] = fmaxf(acc, 0.f);
  __syncthreads();
  if (tid < 10){
    float a3 = fb3[tid];
    for (int k = 0; k < 256; k++) a3 += bufA[k]*fw3[k*10 + tid];
    lg[tid] = a3;
  }
  __syncthreads();
  if (tid < 10){
    float m = lg[0];
    #pragma unroll
    for (int j = 1; j < 10; j++) m = fmaxf(m, lg[j]);
    float s = 0.f;
    #pragma unroll
    for (int j = 0; j < 10; j++) s += expf(lg[j] - m);
    out[b*10 + tid] = lg[tid] - m - logf(s);
  }
}

extern "C" void kernel_launch(void* const* d_in, const int* in_sizes, int n_in,
                              void* d_out, int out_size, void* d_ws, size_t ws_size,
                              hipStream_t stream)
{
  const float* x   = (const float*)d_in[0];
  const float* qst = (const float*)d_in[1];
  const float* cw1 = (const float*)d_in[2];
  const float* cb1 = (const float*)d_in[3];
  const float* bg1 = (const float*)d_in[4];
  const float* bb1 = (const float*)d_in[5];
  const float* cw2 = (const float*)d_in[6];
  const float* cb2 = (const float*)d_in[7];
  const float* bg2 = (const float*)d_in[8];
  const float* bb2 = (const float*)d_in[9];
  const float* cw3 = (const float*)d_in[10];
  const float* cb3 = (const float*)d_in[11];
  const float* bg3 = (const float*)d_in[12];
  const float* bb3 = (const float*)d_in[13];
  const float* cw4 = (const float*)d_in[14];
  const float* cb4 = (const float*)d_in[15];
  const float* bg4 = (const float*)d_in[16];
  const float* bb4 = (const float*)d_in[17];
  const float* gw1 = (const float*)d_in[18];
  const float* gb1 = (const float*)d_in[19];
  const float* gw2 = (const float*)d_in[20];
  const float* gb2 = (const float*)d_in[21];
  const float* gw3 = (const float*)d_in[22];
  const float* gb3 = (const float*)d_in[23];
  const float* gw4 = (const float*)d_in[24];
  const float* gb4 = (const float*)d_in[25];
  const float* fw1 = (const float*)d_in[26];
  const float* fb1 = (const float*)d_in[27];
  const float* fw2 = (const float*)d_in[28];
  const float* fb2 = (const float*)d_in[29];
  const float* fw3 = (const float*)d_in[30];
  const float* fb3 = (const float*)d_in[31];

  // workspace layout (floats); total 13,296,832 f = 53.2 MB
  float* wsf    = (float*)d_ws;
  unsigned short* Wf = (unsigned short*)(wsf + 65728);  // 3 x 65536 bf16
  float* stats  = wsf + 164032;            // 4 layers x 8 shadows x 48 = 1536
  float* y1     = wsf + 240832;            // 9,830,400
  float* y2     = wsf + 10071232;          // 2,457,600
  float* y3     = wsf + 12528832;          // 614,400
  float* y4     = wsf + 13143232;          // 153,600

  prep_w_zero<<<768, 256, 0, stream>>>(gw2, gw3, gw4, Wf, stats);
  conv_px<3,8,4><<<dim3(400,3), 256, 0, stream>>>(x, nullptr, nullptr, nullptr, 0.f,
                                               cw1, cb1, y1, stats + 0, 80,80,40,40);
  conv_px<24,8,4><<<dim3(100,3), 256, 0, stream>>>(y1, stats + 0, bg1, bb1, 1.f/409600.f,
                                               cw2, cb2, y2, stats + 384, 40,40,20,20);
  conv_px<24,8,2><<<dim3(50,3), 256, 0, stream>>>(y2, stats + 384, bg2, bb2, 1.f/102400.f,
                                               cw3, cb3, y3, stats + 768, 20,20,10,10);
  conv_px<24,8,1><<<dim3(25,3), 256, 0, stream>>>(y3, stats + 768, bg3, bb3, 1.f/25600.f,
                                              cw4, cb4, y4, stats + 1152, 10,10,5,5);
  g_mega<<<256, 512, 0, stream>>>(y4, stats + 1152, bg4, bb4, qst, gw1, gb1, Wf,
                                  gb2, gb3, gb4, fw1, fb1, fw2, fb2, fw3, fb3,
                                  (float*)d_out);
}

// Round 17
// 270.620 us; speedup vs baseline: 1.0675x; 1.0675x over previous
//
#include <hip/hip_runtime.h>
#include <hip/hip_bf16.h>

// RelationalNet forward, MI355X (gfx950).  5 graph nodes:
// conv1_fat: blocks 0..767 prep gw2/3/4 -> bf16 fragment order; blocks
//            768..1967 conv1 (PX=4, COG=8x3 flattened) + non-atomic pstats.
// conv2..4:  PX px/thread conv (R16 bodies); preamble = parallel 48ch x 5thr
//            reduce of prev pstats -> BN fold; epilogue non-atomic pstats
//            (every slot written -> no zero-init, no atomics, no memset).
// g_mega (1 block/batch, 512 thr): BN4 reduce(25) + obj + A'/Bm LDS -> 5 x
//            {act-init; 3 layers 256x256 bf16 MFMA; row-sum} -> inline f_phi.
// Workspace: 13,296,832 floats = 53.2 MB.

typedef __attribute__((ext_vector_type(8))) short short8;
typedef __attribute__((ext_vector_type(4))) float floatx4;

__device__ __forceinline__ unsigned short f2bf(float v){
  union { float f; unsigned int u; } c; c.f = v;
  unsigned int u = c.u;
  u += 0x7FFFu + ((u >> 16) & 1u);   // round-to-nearest-even
  return (unsigned short)(u >> 16);
}

// ---- conv1 fat kernel: weight prep (blocks 0..767) + conv1 PX=4 (768..1967) ----
// wf[w][((kk*16 + t)*64 + lane)*8 + i] = W[kk*32 + (lane>>4)*8 + i][t*16 + (lane&15)]
__global__ __launch_bounds__(256) void conv1_fat(
    const float* __restrict__ gw2, const float* __restrict__ gw3,
    const float* __restrict__ gw4, unsigned short* __restrict__ wf,
    const float* __restrict__ x, const float* __restrict__ cw1,
    const float* __restrict__ cb1,
    float* __restrict__ out, float* __restrict__ pstats1)
{
  const int bid = blockIdx.x, tid = threadIdx.x;
  if (bid < 768){
    const int w = bid >> 8;
    const float* gw = (w == 0) ? gw2 : (w == 1) ? gw3 : gw4;
    const int idx = (bid & 255)*256 + tid;
    const int i = idx & 7, lane = (idx >> 3) & 63, t = (idx >> 9) & 15, kk = idx >> 13;
    const int k = kk*32 + (lane >> 4)*8 + i;
    const int c = t*16 + (lane & 15);
    wf[w*65536 + idx] = f2bf(gw[k*256 + c]);
    return;
  }
  __shared__ float psum[4][8], psum2[4][8];
  const int cb = bid - 768;                       // 0..1199
  const int grp = cb / 400, xb = cb % 400;        // co group, x-block
  const int co0 = grp * 8;
  const int idx = xb*256 + tid;                   // 102400 items (PX=4, nw=10)
  const int pw = idx % 10; const int t2 = idx / 10;
  const int oh = t2 % 40;  const int b  = t2 / 40;
  const int ow0 = pw * 4;
  const float* cwb = cw1 + co0*3*9;               // wave-uniform -> s_load
  float acc[4][8];
  #pragma unroll
  for (int j = 0; j < 4; j++)
    #pragma unroll
    for (int g = 0; g < 8; g++) acc[j][g] = cb1[co0 + g];
  #pragma unroll
  for (int ci = 0; ci < 3; ci++){
    const float* ip = x + ((long)(b*3 + ci))*6400;
    float v[3][9];
    #pragma unroll
    for (int kh = 0; kh < 3; kh++){
      const int ih = oh*2 - 1 + kh;
      const bool hok = (ih >= 0);
      #pragma unroll
      for (int c9 = 0; c9 < 9; c9++){
        const int iw = ow0*2 - 1 + c9;
        const bool ok = hok & (iw >= 0);
        v[kh][c9] = ok ? ip[ok ? ih*80 + iw : 0] : 0.f;   // clamped addr, zero-pad
      }
    }
    #pragma unroll
    for (int g = 0; g < 8; g++){
      #pragma unroll
      for (int kh = 0; kh < 3; kh++){
        const float w0 = cwb[(g*3 + ci)*9 + kh*3 + 0];
        const float w1 = cwb[(g*3 + ci)*9 + kh*3 + 1];
        const float w2 = cwb[(g*3 + ci)*9 + kh*3 + 2];
        #pragma unroll
        for (int j = 0; j < 4; j++)
          acc[j][g] += v[kh][2*j]*w0 + v[kh][2*j+1]*w1 + v[kh][2*j+2]*w2;
      }
    }
  }
  const int wave = tid >> 6, lane = tid & 63;
  float s[8], s2[8];
  #pragma unroll
  for (int g = 0; g < 8; g++){
    float tmp[4], a = 0.f, a2 = 0.f;
    #pragma unroll
    for (int j = 0; j < 4; j++){
      tmp[j] = fmaxf(acc[j][g], 0.f);
      a += tmp[j]; a2 += tmp[j]*tmp[j];
    }
    *(float4*)&out[(((long)b*24 + co0 + g)*40 + oh)*40 + ow0] =
        make_float4(tmp[0], tmp[1], tmp[2], tmp[3]);
    s[g] = a; s2[g] = a2;
  }
  #pragma unroll
  for (int g = 0; g < 8; g++){
    float a = s[g], a2 = s2[g];
    for (int off = 32; off; off >>= 1){ a += __shfl_down(a, off); a2 += __shfl_down(a2, off); }
    if (lane == 0){ psum[wave][g] = a; psum2[wave][g] = a2; }
  }
  __syncthreads();
  if (tid < 8){
    pstats1[(co0 + tid)*400 + xb]      = psum[0][tid] + psum[1][tid] + psum[2][tid] + psum[3][tid];
    pstats1[(24 + co0 + tid)*400 + xb] = psum2[0][tid] + psum2[1][tid] + psum2[2][tid] + psum2[3][tid];
  }
}

// ------- conv + relu; parallel pstats preamble; non-atomic pstats epilogue -------
template<int CI, int COG, int PX, int NIN, int NOUT>
__global__ __launch_bounds__(256) void conv_px(
    const float* __restrict__ in, const float* __restrict__ pst_in,
    const float* __restrict__ gprev, const float* __restrict__ bprev, float invN,
    const float* __restrict__ cw, const float* __restrict__ cb,
    float* __restrict__ out, float* __restrict__ pst_out,
    int H, int W, int OH, int OW)
{
  const int co0 = blockIdx.y * COG;
  __shared__ float psub[48][5];
  __shared__ float ssm[2*CI];
  __shared__ float psum[4][COG], psum2[4][COG];
  const int tid = threadIdx.x;
  // parallel stats reduce: 48 channels x 5 threads (chunk even for 400/100/50)
  if (tid < 240){
    const int c = tid / 5, sub = tid % 5;
    constexpr int chunk = NIN / 5;
    const float* p = pst_in + c*NIN + sub*chunk;
    float S0 = 0.f, S1 = 0.f;
    #pragma unroll 2
    for (int j = 0; j < chunk; j += 2){ S0 += p[j]; S1 += p[j+1]; }
    psub[c][sub] = S0 + S1;
  }
  __syncthreads();
  if (tid < 24){
    const float Sm  = psub[tid][0] + psub[tid][1] + psub[tid][2] + psub[tid][3] + psub[tid][4];
    const float S2m = psub[24+tid][0] + psub[24+tid][1] + psub[24+tid][2] + psub[24+tid][3] + psub[24+tid][4];
    const float mean = Sm*invN;
    const float var  = S2m*invN - mean*mean;     // biased var (ddof=0) = jnp.var
    const float rs   = rsqrtf(var + 1e-5f);
    const float sc   = gprev[tid]*rs;
    ssm[tid] = sc; ssm[CI + tid] = bprev[tid] - mean*sc;
  }
  __syncthreads();
  const int nw = OW / PX;                        // exact
  const int idx = blockIdx.x*256 + tid;          // grids exact multiples of 256
  const int pw = idx % nw; const int t2 = idx / nw;
  const int oh = t2 % OH;  const int b  = t2 / OH;
  const int ow0 = pw * PX;
  const float* cwb = cw + co0*CI*9;              // wave-uniform -> s_load
  constexpr int NC = 2*PX + 1;
  float acc[PX][COG];
  #pragma unroll
  for (int j = 0; j < PX; j++)
    #pragma unroll
    for (int g = 0; g < COG; g++) acc[j][g] = cb[co0 + g];

  #pragma unroll 1                               // dynamic ci: 72 live weights
  for (int ci = 0; ci < CI; ci++){
    const float* ip = in + ((long)(b*CI + ci))*H*W;
    const float sc = ssm[ci], sh2 = ssm[CI + ci];
    float v[3][NC];
    #pragma unroll
    for (int kh = 0; kh < 3; kh++){
      const int ih = oh*2 - 1 + kh;              // only <0 possible
      const bool hok = (ih >= 0);
      #pragma unroll
      for (int c9 = 0; c9 < NC; c9++){
        const int iw = ow0*2 - 1 + c9;           // only <0 possible
        const bool ok = hok & (iw >= 0);
        const float raw = ip[ok ? ih*W + iw : 0];    // unconditional, clamped addr
        v[kh][c9] = ok ? raw*sc + sh2 : 0.f;         // zero-pad after BN fold
      }
    }
    #pragma unroll
    for (int g = 0; g < COG; g++){
      #pragma unroll
      for (int kh = 0; kh < 3; kh++){
        const float w0 = cwb[(g*CI + ci)*9 + kh*3 + 0];
        const float w1 = cwb[(g*CI + ci)*9 + kh*3 + 1];
        const float w2 = cwb[(g*CI + ci)*9 + kh*3 + 2];
        #pragma unroll
        for (int j = 0; j < PX; j++)
          acc[j][g] += v[kh][2*j]*w0 + v[kh][2*j+1]*w1 + v[kh][2*j+2]*w2;
      }
    }
  }

  const int wave = tid >> 6, lane = tid & 63;
  float s[COG], s2[COG];
  #pragma unroll
  for (int g = 0; g < COG; g++){
    float tmp[PX], a = 0.f, a2 = 0.f;
    #pragma unroll
    for (int j = 0; j < PX; j++){
      tmp[j] = fmaxf(acc[j][g], 0.f);
      a += tmp[j]; a2 += tmp[j]*tmp[j];
    }
    float* op = &out[(((long)b*24 + co0 + g)*OH + oh)*OW + ow0];
    if constexpr (PX == 4) *(float4*)op = make_float4(tmp[0], tmp[1], tmp[2], tmp[3]);
    else if constexpr (PX == 2) *(float2*)op = make_float2(tmp[0], tmp[1]);
    else op[0] = tmp[0];
    s[g] = a; s2[g] = a2;
  }
  #pragma unroll
  for (int g = 0; g < COG; g++){
    float a = s[g], a2 = s2[g];
    for (int off = 32; off; off >>= 1){ a += __shfl_down(a, off); a2 += __shfl_down(a2, off); }
    if (lane == 0){ psum[wave][g] = a; psum2[wave][g] = a2; }
  }
  __syncthreads();
  if (tid < COG){
    pst_out[(co0 + tid)*NOUT + blockIdx.x]      = psum[0][tid] + psum[1][tid] + psum[2][tid] + psum[3][tid];
    pst_out[(24 + co0 + tid)*NOUT + blockIdx.x] = psum2[0][tid] + psum2[1][tid] + psum2[2][tid] + psum2[3][tid];
  }
}

// ------ g_mega: BN4 + obj + A'/Bm (LDS) + 5x(act-init; 3-layer MFMA; rowsum) + f_phi ------
__global__ __launch_bounds__(512) void g_mega(
    const float* __restrict__ y4, const float* __restrict__ pstats4,
    const float* __restrict__ bg4, const float* __restrict__ bb4,
    const float* __restrict__ qst, const float* __restrict__ gw1,
    const float* __restrict__ gb1,
    const unsigned short* __restrict__ Wf,
    const float* __restrict__ gb2, const float* __restrict__ gb3, const float* __restrict__ gb4,
    const float* __restrict__ fw1, const float* __restrict__ fb1,
    const float* __restrict__ fw2, const float* __restrict__ fb2,
    const float* __restrict__ fw3, const float* __restrict__ fb3,
    float* __restrict__ out)
{
  __shared__ __align__(16) short act[128*256];      // 64 KB
  __shared__ __align__(16) float A_lds[25][260];    // 26 KB (A + Qv folded)
  __shared__ __align__(16) float Bm_lds[25][260];   // 26 KB
  __shared__ float obj[25][26];
  __shared__ float ssum[48];
  __shared__ float ssm[48];
  __shared__ float scratch[512];
  __shared__ __align__(16) float bufA[256], bufB[256];
  __shared__ float lg[10];

  const int b = blockIdx.x, tid = threadIdx.x;
  char* actB = (char*)act;
  const int wave = tid >> 6, lane = tid & 63;
  const int lmod = lane & 15, ldiv = lane >> 4;
  const int wm = wave >> 2, wn = wave & 3;          // 2 x 4 wave grid

  // ---- BN4 reduce (25 non-atomic partials) + finalize ----
  if (tid < 48){
    float S = 0.f;
    const float* p = pstats4 + tid*25;
    #pragma unroll
    for (int j = 0; j < 25; j++) S += p[j];
    ssum[tid] = S;
  }
  __syncthreads();
  if (tid < 24){
    const float mean = ssum[tid]*(1.f/6400.f);
    const float var  = ssum[24 + tid]*(1.f/6400.f) - mean*mean;
    const float rs   = rsqrtf(var + 1e-5f);
    const float sc   = bg4[tid]*rs;
    ssm[tid] = sc; ssm[24 + tid] = bb4[tid] - mean*sc;
  }
  __syncthreads();
  // ---- obj (BN-folded y4 + coords) ----
  for (int j = tid; j < 600; j += 512){
    const int q = j/24, c = j%24;
    obj[q][c] = ssm[c]*y4[((long)(b*24 + c))*25 + q] + ssm[24 + c];
  }
  if (tid < 50){
    const int q = tid >> 1;
    obj[q][24 + (tid & 1)] = (tid & 1) ? (float)(q%5 - 2)*0.5f : (float)(q/5 - 2)*0.5f;
  }
  __syncthreads();
  // ---- A'(=A+Qv), Bm into LDS; halves split the q range ----
  {
    const int n = tid & 255, half = tid >> 8;
    float wa[26], wb[26];
    #pragma unroll
    for (int c = 0; c < 26; c++){ wa[c] = gw1[c*256 + n]; wb[c] = gw1[(26 + c)*256 + n]; }
    float qv = gb1[n];
    #pragma unroll
    for (int j = 0; j < 11; j++) qv += qst[b*11 + j]*gw1[(52 + j)*256 + n];
    const int q0 = half ? 13 : 0, q1 = half ? 25 : 13;
    for (int q = q0; q < q1; q++){
      float a = qv, bm = 0.f;
      #pragma unroll
      for (int c = 0; c < 26; c++){ const float o = obj[q][c]; a += o*wa[c]; bm += o*wb[c]; }
      A_lds[q][n] = a; Bm_lds[q][n] = bm;
    }
  }
  __syncthreads();

  float gsum = 0.f;
  for (int blk = 0; blk < 5; blk++){
    const int rowbase = blk * 128;
    const int nrows = min(128, 625 - rowbase);      // last chunk: 113
    // ---- act-init: act = relu(A'[q] + Bm[p]), bf16, swizzled ----
    {
      const int r  = tid >> 2;
      const int q4 = tid & 3;
      if (r < nrows){
        const int row = rowbase + r;                // pair index p*25+q
        const float* ap = &A_lds [row % 25][q4*4];
        const float* bp = &Bm_lds[row / 25][q4*4];
        #pragma unroll
        for (int j = 0; j < 16; j++){
          const int c = j*16;
          floatx4 av = *(const floatx4*)(ap + c);
          floatx4 bv = *(const floatx4*)(bp + c);
          unsigned int p0 = (unsigned int)f2bf(fmaxf(av.x+bv.x, 0.f))
                          | ((unsigned int)f2bf(fmaxf(av.y+bv.y, 0.f)) << 16);
          unsigned int p1 = (unsigned int)f2bf(fmaxf(av.z+bv.z, 0.f))
                          | ((unsigned int)f2bf(fmaxf(av.w+bv.w, 0.f)) << 16);
          const int byte = (r*512 + (c + q4*4)*2) ^ ((r & 7) << 4);
          *(uint2*)(actB + byte) = make_uint2(p0, p1);
        }
      } else {
        #pragma unroll
        for (int j = 0; j < 16; j++){
          const int byte = (r*512 + (j*16 + q4*4)*2) ^ ((r & 7) << 4);
          *(uint2*)(actB + byte) = make_uint2(0u, 0u); // padded rows zero (masked)
        }
      }
    }
    __syncthreads();

    for (int L = 0; L < 3; L++){
      floatx4 acc[4][4];
      #pragma unroll
      for (int m = 0; m < 4; m++)
        #pragma unroll
        for (int n = 0; n < 4; n++)
          acc[m][n] = (floatx4){0.f,0.f,0.f,0.f};
      const short8* wlayer = (const short8*)Wf + (long)L*8192;
      #pragma unroll
      for (int kk = 0; kk < 8; kk++){
        short8 bf[4];
        #pragma unroll
        for (int n = 0; n < 4; n++)
          bf[n] = wlayer[(kk*16 + wn*4 + n)*64 + lane];   // coalesced, L2-hot
        short8 af[4];
        #pragma unroll
        for (int m = 0; m < 4; m++){
          const int arow  = wm*64 + m*16 + lmod;
          const int abyte = (arow*512 + kk*64 + ldiv*16) ^ ((arow & 7) << 4);
          af[m] = *(const short8*)(actB + abyte);
        }
        #pragma unroll
        for (int n = 0; n < 4; n++)
          #pragma unroll
          for (int m = 0; m < 4; m++)
            acc[m][n] = __builtin_amdgcn_mfma_f32_16x16x32_bf16(af[m], bf[n], acc[m][n], 0, 0, 0);
      }

      if (L < 2){
        const float* bias = (L == 0) ? gb2 : gb3;
        __syncthreads();   // WAR: all act reads done before overwrite
        // D layout: row = m*16 + ldiv*4 + i, col = (wn*4+n)*16 + lmod   [m89]
        #pragma unroll
        for (int n = 0; n < 4; n++){
          const int c = (wn*4 + n)*16 + lmod;
          const float bv = bias[c];
          #pragma unroll
          for (int m = 0; m < 4; m++){
            #pragma unroll
            for (int i = 0; i < 4; i++){
              const int row = wm*64 + m*16 + ldiv*4 + i;
              const float v = fmaxf(acc[m][n][i] + bv, 0.f);
              const int byte = (row*512 + c*2) ^ ((row & 7) << 4);
              *(short*)(actB + byte) = (short)f2bf(v);
            }
          }
        }
        __syncthreads();   // new act visible
      } else {
        __syncthreads();   // all act reads + prior scratch reads done
        #pragma unroll
        for (int n = 0; n < 4; n++){
          const int c = (wn*4 + n)*16 + lmod;
          const float bv = gb4[c];
          float sv = 0.f;
          #pragma unroll
          for (int m = 0; m < 4; m++){
            #pragma unroll
            for (int i = 0; i < 4; i++){
              const int row = wm*64 + m*16 + ldiv*4 + i;
              const float v = fmaxf(acc[m][n][i] + bv, 0.f);
              if (row < nrows) sv += v;             // mask padded rows
            }
          }
          sv += __shfl_xor(sv, 16);
          sv += __shfl_xor(sv, 32);
          if (ldiv == 0) scratch[wm*256 + c] = sv;
        }
        __syncthreads();
        if (tid < 256) gsum += scratch[tid] + scratch[256 + tid];
      }
    }
  }

  // ---- inline f_phi + log_softmax ----
  if (tid < 256) bufA[tid] = gsum;
  __syncthreads();
  const int n = tid & 255;
  float acc = 0.f;
  if (tid < 256){
    acc = fb1[n];
    const float4* pa = (const float4*)bufA;
    #pragma unroll 8
    for (int k4 = 0; k4 < 64; k4++){
      const float4 a = pa[k4];
      acc += a.x*fw1[(k4*4 + 0)*256 + n];
      acc += a.y*fw1[(k4*4 + 1)*256 + n];
      acc += a.z*fw1[(k4*4 + 2)*256 + n];
      acc += a.w*fw1[(k4*4 + 3)*256 + n];
    }
    bufB[n] = fmaxf(acc, 0.f);
  }
  __syncthreads();
  if (tid < 256){
    acc = fb2[n];
    const float4* pb = (const float4*)bufB;
    #pragma unroll 8
    for (int k4 = 0; k4 < 64; k4++){
      const float4 a = pb[k4];
      acc += a.x*fw2[(k4*4 + 0)*256 + n];
      acc += a.y*fw2[(k4*4 + 1)*256 + n];
      acc += a.z*fw2[(k4*4 + 2)*256 + n];
      acc += a.w*fw2[(k4*4 + 3)*256 + n];
    }
  }
  __syncthreads();          // bufB reads done
  if (tid < 256) bufA[n] = fmaxf(acc, 0.f);
  __syncthreads();
  if (tid < 10){
    float a3 = fb3[tid];
    for (int k = 0; k < 256; k++) a3 += bufA[k]*fw3[k*10 + tid];
    lg[tid] = a3;
  }
  __syncthreads();
  if (tid < 10){
    float m = lg[0];
    #pragma unroll
    for (int j = 1; j < 10; j++) m = fmaxf(m, lg[j]);
    float s = 0.f;
    #pragma unroll
    for (int j = 0; j < 10; j++) s += expf(lg[j] - m);
    out[b*10 + tid] = lg[tid] - m - logf(s);
  }
}

extern "C" void kernel_launch(void* const* d_in, const int* in_sizes, int n_in,
                              void* d_out, int out_size, void* d_ws, size_t ws_size,
                              hipStream_t stream)
{
  const float* x   = (const float*)d_in[0];
  const float* qst = (const float*)d_in[1];
  const float* cw1 = (const float*)d_in[2];
  const float* cb1 = (const float*)d_in[3];
  const float* bg1 = (const float*)d_in[4];
  const float* bb1 = (const float*)d_in[5];
  const float* cw2 = (const float*)d_in[6];
  const float* cb2 = (const float*)d_in[7];
  const float* bg2 = (const float*)d_in[8];
  const float* bb2 = (const float*)d_in[9];
  const float* cw3 = (const float*)d_in[10];
  const float* cb3 = (const float*)d_in[11];
  const float* bg3 = (const float*)d_in[12];
  const float* bb3 = (const float*)d_in[13];
  const float* cw4 = (const float*)d_in[14];
  const float* cb4 = (const float*)d_in[15];
  const float* bg4 = (const float*)d_in[16];
  const float* bb4 = (const float*)d_in[17];
  const float* gw1 = (const float*)d_in[18];
  const float* gb1 = (const float*)d_in[19];
  const float* gw2 = (const float*)d_in[20];
  const float* gb2 = (const float*)d_in[21];
  const float* gw3 = (const float*)d_in[22];
  const float* gb3 = (const float*)d_in[23];
  const float* gw4 = (const float*)d_in[24];
  const float* gb4 = (const float*)d_in[25];
  const float* fw1 = (const float*)d_in[26];
  const float* fb1 = (const float*)d_in[27];
  const float* fw2 = (const float*)d_in[28];
  const float* fb2 = (const float*)d_in[29];
  const float* fw3 = (const float*)d_in[30];
  const float* fb3 = (const float*)d_in[31];

  // workspace layout (floats); total 13,296,832 f = 53.2 MB
  float* wsf     = (float*)d_ws;
  float* pstats1 = wsf + 0;                // 48 x 400 = 19200
  float* pstats2 = wsf + 19200;            // 48 x 100 = 4800
  float* pstats3 = wsf + 24000;            // 48 x 50  = 2400
  float* pstats4 = wsf + 26400;            // 48 x 25  = 1200
  unsigned short* Wf = (unsigned short*)(wsf + 65728);  // 3 x 65536 bf16
  float* y1      = wsf + 240832;           // 9,830,400
  float* y2      = wsf + 10071232;         // 2,457,600
  float* y3      = wsf + 12528832;         // 614,400
  float* y4      = wsf + 13143232;         // 153,600

  conv1_fat<<<1968, 256, 0, stream>>>(gw2, gw3, gw4, Wf, x, cw1, cb1, y1, pstats1);
  conv_px<24,8,4,400,100><<<dim3(100,3), 256, 0, stream>>>(
      y1, pstats1, bg1, bb1, 1.f/409600.f, cw2, cb2, y2, pstats2, 40,40,20,20);
  conv_px<24,8,2,100,50><<<dim3(50,3), 256, 0, stream>>>(
      y2, pstats2, bg2, bb2, 1.f/102400.f, cw3, cb3, y3, pstats3, 20,20,10,10);
  conv_px<24,8,1,50,25><<<dim3(25,3), 256, 0, stream>>>(
      y3, pstats3, bg3, bb3, 1.f/25600.f, cw4, cb4, y4, pstats4, 10,10,5,5);
  g_mega<<<256, 512, 0, stream>>>(y4, pstats4, bg4, bb4, qst, gw1, gb1, Wf,
                                  gb2, gb3, gb4, fw1, fb1, fw2, fb2, fw3, fb3,
                                  (float*)d_out);
}